// Round 1
// baseline (214.027 us; speedup 1.0000x reference)
//
#include <hip/hip_runtime.h>
#include <hip/hip_bf16.h>
#include <stdint.h>

typedef __bf16 bf16;
typedef __bf16 bf16x8 __attribute__((ext_vector_type(8)));
typedef float f32x4 __attribute__((ext_vector_type(4)));
typedef float f32x16 __attribute__((ext_vector_type(16)));

#define HIDDEN 1024
#define HEADS  16
#define HD     64
#define SEQ    2048
#define BATCH  2
#define NTOK   (BATCH*SEQ)
#define E3     (3*HIDDEN)

static __device__ __forceinline__ uint32_t pkbf(float a, float b) {
  union { bf16 h[2]; uint32_t u; } x;
  x.h[0] = (bf16)a; x.h[1] = (bf16)b;
  return x.u;
}

// ---------------- f32 -> bf16 convert of x, w_qkv, w_out ----------------
__global__ __launch_bounds__(256) void k_convert(
    const float* __restrict__ x, const float* __restrict__ wqkv, const float* __restrict__ wout,
    bf16* __restrict__ xb, bf16* __restrict__ wqkvb, bf16* __restrict__ woutb)
{
  const int NX = NTOK*HIDDEN/4, NW = E3*HIDDEN/4;
  int i = blockIdx.x*256 + threadIdx.x;
  const float4* s; bf16* d; int o;
  if (i < NX)            { s=(const float4*)x;    d=xb;    o=i; }
  else if (i < NX+NW)    { s=(const float4*)wqkv; d=wqkvb; o=i-NX; }
  else                   { s=(const float4*)wout; d=woutb; o=i-NX-NW; }
  float4 v = s[o];
  union { bf16 b[4]; uint2 u; } p;
  p.b[0]=(bf16)v.x; p.b[1]=(bf16)v.y; p.b[2]=(bf16)v.z; p.b[3]=(bf16)v.w;
  *(uint2*)(d + (size_t)o*4) = p.u;
}

// ---------------- bf16 GEMM  C[M,N] = A[M,K] * B[N,K]^T  (m97-style) ----------------
// EPI=0: scatter to Q/K/V head layout (Q scaled by 1/8).  EPI=1: f32 out.
template<int EPI>
__global__ __launch_bounds__(256) void k_gemm(
    const bf16* __restrict__ A, const bf16* __restrict__ B,
    bf16* __restrict__ Oq, bf16* __restrict__ Ok, bf16* __restrict__ Ov,
    float* __restrict__ Of, int M, int N, int K, int nbn)
{
  __shared__ bf16 As[128*32];
  __shared__ bf16 Bs[128*32];
  const int t = threadIdx.x;
  const int lane = t & 63;
  const int w = t >> 6;
  const int g = lane >> 4;
  const int l15 = lane & 15;
  const int wm = (w >> 1) * 64, wn = (w & 1) * 64;
  const int bm = blockIdx.x / nbn, bn = blockIdx.x % nbn;
  const int brow = bm*128, bcol = bn*128;

  f32x4 acc[4][4];
  #pragma unroll
  for (int mi=0;mi<4;mi++)
    #pragma unroll
    for (int ni=0;ni<4;ni++)
      #pragma unroll
      for (int r=0;r<4;r++) acc[mi][ni][r] = 0.f;

  const int nk = K >> 5;
  for (int kt = 0; kt < nk; ++kt) {
    // stage A,B tiles: 512 x 16B chunks each; chunk ch -> row=ch>>2, part=ch&3; LDS linear.
    {
      int ch = w*128 + lane;
      const bf16* ga = A + (size_t)(brow + (ch>>2))*K + kt*32 + (ch&3)*8;
      __builtin_amdgcn_global_load_lds((const uint32_t*)ga, (uint32_t*)(As + (w*128)*8), 16, 0, 0);
      const bf16* gb = B + (size_t)(bcol + (ch>>2))*K + kt*32 + (ch&3)*8;
      __builtin_amdgcn_global_load_lds((const uint32_t*)gb, (uint32_t*)(Bs + (w*128)*8), 16, 0, 0);
      ch += 64;
      ga = A + (size_t)(brow + (ch>>2))*K + kt*32 + (ch&3)*8;
      __builtin_amdgcn_global_load_lds((const uint32_t*)ga, (uint32_t*)(As + (w*128+64)*8), 16, 0, 0);
      gb = B + (size_t)(bcol + (ch>>2))*K + kt*32 + (ch&3)*8;
      __builtin_amdgcn_global_load_lds((const uint32_t*)gb, (uint32_t*)(Bs + (w*128+64)*8), 16, 0, 0);
    }
    __syncthreads();
    bf16x8 af[4], bfr[4];
    #pragma unroll
    for (int mi=0;mi<4;mi++) af[mi]  = *(const bf16x8*)(As + (wm + mi*16 + l15)*32 + g*8);
    #pragma unroll
    for (int ni=0;ni<4;ni++) bfr[ni] = *(const bf16x8*)(Bs + (wn + ni*16 + l15)*32 + g*8);
    #pragma unroll
    for (int mi=0;mi<4;mi++)
      #pragma unroll
      for (int ni=0;ni<4;ni++)
        acc[mi][ni] = __builtin_amdgcn_mfma_f32_16x16x32_bf16(af[mi], bfr[ni], acc[mi][ni], 0, 0, 0);
    __syncthreads();
  }

  // epilogue: D layout: row m = 4*g + reg (+16*mi +wm), col n = l15 (+16*ni +wn)
  #pragma unroll
  for (int mi=0;mi<4;mi++) {
    #pragma unroll
    for (int ni=0;ni<4;ni++) {
      #pragma unroll
      for (int r=0;r<4;r++) {
        float val = acc[mi][ni][r];
        int m = brow + wm + mi*16 + 4*g + r;
        int e = bcol + wn + ni*16 + l15;
        if (EPI == 0) {
          int part = e >> 10, we = e & 1023;
          int hh = we >> 6, dd = we & 63;
          int b = m >> 11, sb = m & 2047;
          size_t idx = (((size_t)b*HEADS + hh)*SEQ + sb)*HD + dd;
          if (part == 0)      Oq[idx] = (bf16)(val * 0.125f);   // fold softmax scale into Q (exact)
          else if (part == 1) Ok[idx] = (bf16)val;
          else                Ov[idx] = (bf16)val;
        } else {
          Of[(size_t)m*HIDDEN + e] = val;
        }
      }
    }
  }
}

// ---------------- flash attention, swapped QK^T, 32x32x16 MFMA ----------------
// grid: 32 bh * 16 qblocks; block: 4 waves, each wave owns 32 q rows.
__global__ __launch_bounds__(256) void k_attn(
    const bf16* __restrict__ Qg, const bf16* __restrict__ Kg, const bf16* __restrict__ Vg,
    bf16* __restrict__ Og)
{
  __shared__ bf16 Kl[64*64];   // [kv][d], rows XOR-swizzled by ((row&7)<<4) bytes
  __shared__ bf16 Vt[64*64];   // [d][kv], rows XOR-swizzled by ((row&7)<<4) bytes
  const int t = threadIdx.x;
  const int lane = t & 63;
  const int w = t >> 6;
  const int h = lane >> 5;       // wave half
  const int q = lane & 31;       // this lane's q row (within wave tile)
  const int bh = blockIdx.x >> 4;
  const int qb = blockIdx.x & 15;
  const int q0 = qb*128 + w*32;
  const size_t bhS = (size_t)bh * SEQ * HD;

  // Q fragments (B-operand), hoisted: k-slot (h,j) -> d = 16s + 8h + j
  bf16x8 qf[4];
  const bf16* qrow = Qg + bhS + (size_t)(q0 + q)*HD;
  #pragma unroll
  for (int s=0;s<4;s++) qf[s] = *(const bf16x8*)(qrow + 16*s + 8*h);

  f32x16 ot[2];
  #pragma unroll
  for (int mf=0;mf<2;mf++)
    #pragma unroll
    for (int r=0;r<16;r++) ot[mf][r]=0.f;
  float mrun = -3.0e38f, lrun = 0.f;

  for (int it=0; it<SEQ/64; ++it) {
    __syncthreads();
    { // K tile via global_load_lds, source pre-swizzled (16B-granular XOR)
      int ch = w*128 + lane;
      int row = ch>>3, o16 = ch&7;
      const bf16* gp = Kg + bhS + (size_t)(it*64+row)*HD + ((o16*8) ^ ((row&7)*8));
      __builtin_amdgcn_global_load_lds((const uint32_t*)gp, (uint32_t*)(Kl + (w*128)*8), 16, 0, 0);
      ch += 64; row = ch>>3; o16 = ch&7;
      gp = Kg + bhS + (size_t)(it*64+row)*HD + ((o16*8) ^ ((row&7)*8));
      __builtin_amdgcn_global_load_lds((const uint32_t*)gp, (uint32_t*)(Kl + (w*128+64)*8), 16, 0, 0);
    }
    { // V tile, reg-staged transposed into Vt[d][kv] (u32 = two adjacent kv)
      int kv0 = (t & 31)*2, d0 = (t>>5)*8;
      const bf16* vg = Vg + bhS + (size_t)(it*64 + kv0)*HD + d0;
      uint4 va = *(const uint4*)vg;
      uint4 vb = *(const uint4*)(vg + HD);
      const uint32_t* pa = (const uint32_t*)&va;
      const uint32_t* pb = (const uint32_t*)&vb;
      #pragma unroll
      for (int jj=0;jj<8;jj++) {
        int dd = d0 + jj;
        uint32_t lo = (jj&1) ? (pa[jj>>1] >> 16) : (pa[jj>>1] & 0xffffu);
        uint32_t hi = (jj&1) ? (pb[jj>>1] >> 16) : (pb[jj>>1] & 0xffffu);
        int byte = (dd*128 + kv0*2) ^ ((dd&7)<<4);
        *(uint32_t*)((char*)Vt + byte) = lo | (hi<<16);
      }
    }
    __syncthreads();

    // QK^T swapped: sf = K * Q^T  -> scores^T: lane has q = lane&31, kv along regs
    f32x16 sf[2];
    #pragma unroll
    for (int mf=0;mf<2;mf++)
      #pragma unroll
      for (int r=0;r<16;r++) sf[mf][r]=0.f;
    #pragma unroll
    for (int s=0;s<4;s++) {
      #pragma unroll
      for (int mf=0;mf<2;mf++) {
        int row = mf*32 + q;
        int byte = (row*128 + 32*s + 16*h) ^ ((row&7)<<4);
        bf16x8 kf = *(const bf16x8*)((const char*)Kl + byte);
        sf[mf] = __builtin_amdgcn_mfma_f32_32x32x16_bf16(kf, qf[s], sf[mf], 0,0,0);
      }
    }

    // online softmax: row q is lane-local (32 regs) + one xor32 exchange
    float pm = -3.0e38f;
    #pragma unroll
    for (int mf=0;mf<2;mf++)
      #pragma unroll
      for (int r=0;r<16;r++) pm = fmaxf(pm, sf[mf][r]);
    pm = fmaxf(pm, __shfl_xor(pm, 32, 64));
    float mnew = fmaxf(mrun, pm);
    float alpha = __expf(mrun - mnew);
    float rs = 0.f;
    #pragma unroll
    for (int mf=0;mf<2;mf++)
      #pragma unroll
      for (int r=0;r<16;r++) { float p = __expf(sf[mf][r]-mnew); sf[mf][r]=p; rs += p; }
    rs += __shfl_xor(rs, 32, 64);
    lrun = lrun*alpha + rs;
    mrun = mnew;
    #pragma unroll
    for (int mf=0;mf<2;mf++)
      #pragma unroll
      for (int r=0;r<16;r++) ot[mf][r] *= alpha;

    // pack P^T (B-operand) + PV: O^T += V^T * P^T
    #pragma unroll
    for (int s=0;s<4;s++) {
      const int f = s>>1, bb = 8*(s&1);
      uint32_t g0A = pkbf(sf[f][bb+0], sf[f][bb+1]);
      uint32_t g0B = pkbf(sf[f][bb+2], sf[f][bb+3]);
      uint32_t g1A = pkbf(sf[f][bb+4], sf[f][bb+5]);
      uint32_t g1B = pkbf(sf[f][bb+6], sf[f][bb+7]);
      uint32_t ownA = h ? g1A : g0A, ownB = h ? g1B : g0B;
      uint32_t sndA = h ? g0A : g1A, sndB = h ? g0B : g1B;
      uint32_t rcvA = __shfl_xor(sndA, 32, 64);
      uint32_t rcvB = __shfl_xor(sndB, 32, 64);
      union { uint32_t u[4]; bf16x8 v; } pf;
      if (h == 0) { pf.u[0]=ownA; pf.u[1]=ownB; pf.u[2]=rcvA; pf.u[3]=rcvB; }
      else        { pf.u[0]=rcvA; pf.u[1]=rcvB; pf.u[2]=ownA; pf.u[3]=ownB; }
      #pragma unroll
      for (int mf=0;mf<2;mf++) {
        int row = mf*32 + q;
        int byte = (row*128 + 32*s + 16*h) ^ ((row&7)<<4);
        bf16x8 vf = *(const bf16x8*)((const char*)Vt + byte);
        ot[mf] = __builtin_amdgcn_mfma_f32_32x32x16_bf16(vf, pf.v, ot[mf], 0,0,0);
      }
    }
  }

  // normalize + store O[token][head*64+d]
  float inv = 1.0f / lrun;
  int b = bh >> 4, head = bh & 15;
  size_t orow = ((size_t)b*SEQ + q0 + q)*HIDDEN + head*HD;
  #pragma unroll
  for (int mf=0;mf<2;mf++)
    #pragma unroll
    for (int r=0;r<16;r++) {
      int dd = mf*32 + (r&3) + 8*(r>>2) + 4*h;
      Og[orow + dd] = (bf16)(ot[mf][r]*inv);
    }
}

extern "C" void kernel_launch(void* const* d_in, const int* in_sizes, int n_in,
                              void* d_out, int out_size, void* d_ws, size_t ws_size,
                              hipStream_t stream)
{
  (void)in_sizes; (void)n_in; (void)out_size; (void)ws_size;
  const float* x    = (const float*)d_in[0];
  const float* wqkv = (const float*)d_in[1];
  const float* wout = (const float*)d_in[2];
  float* out = (float*)d_out;
  char* ws = (char*)d_ws;
  bf16* xb    = (bf16*)(ws);                 //  8 MiB  [4096][1024]
  bf16* wqkvb = (bf16*)(ws + 8388608);       //  6 MiB  [3072][1024]
  bf16* woutb = (bf16*)(ws + 14680064);      //  2 MiB  [1024][1024]
  bf16* Q     = (bf16*)(ws + 16777216);      //  8 MiB  [2][16][2048][64] (pre-scaled 1/8)
  bf16* K     = (bf16*)(ws + 25165824);      //  8 MiB
  bf16* V     = (bf16*)(ws + 33554432);      //  8 MiB
  bf16* O     = (bf16*)(ws + 41943040);      //  8 MiB  [4096][1024]

  k_convert<<<8192, 256, 0, stream>>>(x, wqkv, wout, xb, wqkvb, woutb);
  k_gemm<0><<<32*24, 256, 0, stream>>>(xb, wqkvb, Q, K, V, nullptr, NTOK, E3, HIDDEN, 24);
  k_attn<<<512, 256, 0, stream>>>(Q, K, V, O);
  k_gemm<1><<<32*8, 256, 0, stream>>>(O, woutb, nullptr, nullptr, nullptr, out, NTOK, HIDDEN, HIDDEN, 8);
}